// Round 2
// baseline (1280.956 us; speedup 1.0000x reference)
//
#include <hip/hip_runtime.h>

#define T_TOTAL 4096
#define NT0     3072
#define CH      6144
#define TD_MAXL 1024
#define TDT     32

// d_ws layout: S[0..4095] (fp32), C[4096..5119] (fp32)

__global__ __launch_bounds__(256) void init_kernel(float* __restrict__ Cbuf) {
    int i = blockIdx.x * 256 + threadIdx.x;
    if (i < TD_MAXL) Cbuf[i] = 0.0f;
}

// S[t] = sum_ch x[t,ch]^2   (4096 blocks, one per t)
__global__ __launch_bounds__(256) void s_kernel(const float* __restrict__ x,
                                                float* __restrict__ S) {
    const int t = blockIdx.x;
    const float* row = x + (size_t)t * CH;
    float s = 0.f;
    for (int k = threadIdx.x; k < CH; k += 256) {
        float v = row[k];
        s = fmaf(v, v, s);
    }
    #pragma unroll
    for (int off = 32; off >= 1; off >>= 1) s += __shfl_xor(s, off, 64);
    __shared__ float part[4];
    const int lane = threadIdx.x & 63, wid = threadIdx.x >> 6;
    if (lane == 0) part[wid] = s;
    __syncthreads();
    if (threadIdx.x == 0) S[t] = part[0] + part[1] + part[2] + part[3];
}

// C[td] += sum over (t, ch-chunk) of x[t+td,ch]*x[t,ch]
// 768 blocks linear; XCD-aware mapping: xcd = bid&7 owns 3 contiguous
// 256-ch chunks (4 MB = one XCD L2 per chunk), td-group fastest so the
// ~32 co-resident blocks per XCD share one L2-resident chunk.
__global__ __launch_bounds__(256, 4) void cross_kernel(const float* __restrict__ x,
                                                       float* __restrict__ C) {
    const int bid  = blockIdx.x;          // 0..767
    const int xcd  = bid & 7;
    const int slot = bid >> 3;            // 0..95
    const int y    = xcd * 3 + (slot >> 5);   // ch-chunk 0..23
    const int xg   = slot & 31;               // td-group 0..31

    const int ch  = y * 256 + threadIdx.x;
    const int td0 = xg * TDT;

    const float* base = x + ch;                               // x[t, ch]
    const float* win0 = x + ch + (size_t)td0 * CH;            // x[t+td0, ch]
    const float* winp = x + ch + (size_t)(td0 + TDT) * CH;    // prefetch stream

    float acc[TDT];
    float w[TDT];   // ring buffer: window values x[t+td0 .. t+td0+31]
    #pragma unroll
    for (int j = 0; j < TDT; ++j) {
        acc[j] = 0.f;
        w[j] = win0[(size_t)j * CH];
    }

    for (int t = 0; t < NT0; t += TDT) {
        #pragma unroll
        for (int u = 0; u < TDT; ++u) {
            const float b  = base[(size_t)(t + u) * CH];
            const float nw = winp[(size_t)(t + u) * CH];   // x[t+u+td0+TDT], max idx 4095
            #pragma unroll
            for (int j = 0; j < TDT; ++j)
                acc[j] = fmaf(w[(u + j) & (TDT - 1)], b, acc[j]);
            w[u] = nw;   // slot u becomes the value needed 32 steps later
        }
    }

    // block-reduce each lag, then one atomic per lag
    __shared__ float part[4][TDT];
    const int lane = threadIdx.x & 63, wid = threadIdx.x >> 6;
    #pragma unroll
    for (int j = 0; j < TDT; ++j) {
        float v = acc[j];
        #pragma unroll
        for (int off = 32; off >= 1; off >>= 1) v += __shfl_xor(v, off, 64);
        if (lane == 0) part[wid][j] = v;
    }
    __syncthreads();
    if (threadIdx.x < TDT) {
        const float s = part[0][threadIdx.x] + part[1][threadIdx.x] +
                        part[2][threadIdx.x] + part[3][threadIdx.x];
        atomicAdd(&C[td0 + threadIdx.x], s);
    }
}

// msd[td] = (P[td] + Q - 2*C[td]) / (NT0*CH)   — Kahan-compensated sums
__global__ __launch_bounds__(256) void combine_kernel(const float* __restrict__ S,
                                                      const float* __restrict__ C,
                                                      float* __restrict__ out) {
    const int td = blockIdx.x * 256 + threadIdx.x;
    if (td >= TD_MAXL) return;
    float p = 0.f, pc = 0.f, q = 0.f, qc = 0.f;
    for (int t = 0; t < NT0; ++t) {
        float yp = S[t + td] - pc;
        float tp = p + yp;
        pc = (tp - p) - yp;
        p = tp;
        float yq = S[t] - qc;
        float tq = q + yq;
        qc = (tq - q) - yq;
        q = tq;
    }
    const float inv_M = 1.0f / ((float)NT0 * (float)CH);
    out[td] = (p + q - 2.0f * C[td]) * inv_M;
}

extern "C" void kernel_launch(void* const* d_in, const int* in_sizes, int n_in,
                              void* d_out, int out_size, void* d_ws, size_t ws_size,
                              hipStream_t stream) {
    const float* x = (const float*)d_in[0];
    float* out = (float*)d_out;
    float* S = (float*)d_ws;            // 4096 floats
    float* C = S + T_TOTAL;             // 1024 floats

    init_kernel<<<dim3((TD_MAXL + 255) / 256), dim3(256), 0, stream>>>(C);
    s_kernel<<<dim3(T_TOTAL), dim3(256), 0, stream>>>(x, S);
    cross_kernel<<<dim3(TD_MAXL / TDT * CH / 256), dim3(256), 0, stream>>>(x, C);
    combine_kernel<<<dim3((TD_MAXL + 255) / 256), dim3(256), 0, stream>>>(S, C, out);
}

// Round 4
// 790.252 us; speedup vs baseline: 1.6209x; 1.6209x over previous
//
#include <hip/hip_runtime.h>

#define T_TOTAL 4096
#define NT0     3072
#define CH      6144
#define TD_MAXL 1024
#define TDT     32

// d_ws layout: S[0..4095] (fp32), C[4096..5119] (fp32)

__global__ __launch_bounds__(256) void init_kernel(float* __restrict__ Cbuf) {
    int i = blockIdx.x * 256 + threadIdx.x;
    if (i < TD_MAXL) Cbuf[i] = 0.0f;
}

// S[t] = sum_ch x[t,ch]^2   (4096 blocks, one per t), float4 loads
__global__ __launch_bounds__(256) void s_kernel(const float* __restrict__ x,
                                                float* __restrict__ S) {
    const int t = blockIdx.x;
    const float4* row = (const float4*)(x + (size_t)t * CH);   // 1536 float4
    float s = 0.f;
    for (int k = threadIdx.x; k < CH / 4; k += 256) {
        float4 v = row[k];
        s = fmaf(v.x, v.x, s);
        s = fmaf(v.y, v.y, s);
        s = fmaf(v.z, v.z, s);
        s = fmaf(v.w, v.w, s);
    }
    #pragma unroll
    for (int off = 32; off >= 1; off >>= 1) s += __shfl_xor(s, off, 64);
    __shared__ float part[4];
    const int lane = threadIdx.x & 63, wid = threadIdx.x >> 6;
    if (lane == 0) part[wid] = s;
    __syncthreads();
    if (threadIdx.x == 0) S[t] = part[0] + part[1] + part[2] + part[3];
}

// C[td] += sum over (t, ch-chunk) of x[t+td,ch]*x[t,ch]
// 768 blocks linear; XCD-aware mapping: xcd = bid&7 owns 3 contiguous
// 256-ch chunks (4 MB = one XCD L2 per chunk), td-group fastest.
//
// Ring-buffer steps are macro-expanded with LITERAL u so every w[] index is
// compile-time (rule #20: runtime-indexed arrays -> scratch; round-2 counters
// showed 2.1 GB of spill writes from exactly this).
__global__ __launch_bounds__(256, 2) void cross_kernel(const float* __restrict__ x,
                                                       float* __restrict__ C) {
    const int bid  = blockIdx.x;          // 0..767
    const int xcd  = bid & 7;
    const int slot = bid >> 3;            // 0..95
    const int y    = xcd * 3 + (slot >> 5);   // ch-chunk 0..23
    const int xg   = slot & 31;               // td-group 0..31

    const int ch  = y * 256 + threadIdx.x;
    const int td0 = xg * TDT;

    const float* base = x + ch;                               // x[t, ch]
    const float* win0 = x + ch + (size_t)td0 * CH;            // x[t+td0, ch]
    const float* winp = x + ch + (size_t)(td0 + TDT) * CH;    // next-window stream

    float acc[TDT];
    float w[TDT];   // ring buffer: w[(t%32 + j)&31] == x[t+td0+j, ch]
    #pragma unroll
    for (int j = 0; j < TDT; ++j) {
        acc[j] = 0.f;
        w[j] = win0[(size_t)j * CH];
    }

#define STEP(u) { \
        const float b  = base[(size_t)(t + (u)) * CH]; \
        const float nw = winp[(size_t)(t + (u)) * CH]; \
        acc[ 0] = fmaf(w[((u)+ 0) & 31], b, acc[ 0]); \
        acc[ 1] = fmaf(w[((u)+ 1) & 31], b, acc[ 1]); \
        acc[ 2] = fmaf(w[((u)+ 2) & 31], b, acc[ 2]); \
        acc[ 3] = fmaf(w[((u)+ 3) & 31], b, acc[ 3]); \
        acc[ 4] = fmaf(w[((u)+ 4) & 31], b, acc[ 4]); \
        acc[ 5] = fmaf(w[((u)+ 5) & 31], b, acc[ 5]); \
        acc[ 6] = fmaf(w[((u)+ 6) & 31], b, acc[ 6]); \
        acc[ 7] = fmaf(w[((u)+ 7) & 31], b, acc[ 7]); \
        acc[ 8] = fmaf(w[((u)+ 8) & 31], b, acc[ 8]); \
        acc[ 9] = fmaf(w[((u)+ 9) & 31], b, acc[ 9]); \
        acc[10] = fmaf(w[((u)+10) & 31], b, acc[10]); \
        acc[11] = fmaf(w[((u)+11) & 31], b, acc[11]); \
        acc[12] = fmaf(w[((u)+12) & 31], b, acc[12]); \
        acc[13] = fmaf(w[((u)+13) & 31], b, acc[13]); \
        acc[14] = fmaf(w[((u)+14) & 31], b, acc[14]); \
        acc[15] = fmaf(w[((u)+15) & 31], b, acc[15]); \
        acc[16] = fmaf(w[((u)+16) & 31], b, acc[16]); \
        acc[17] = fmaf(w[((u)+17) & 31], b, acc[17]); \
        acc[18] = fmaf(w[((u)+18) & 31], b, acc[18]); \
        acc[19] = fmaf(w[((u)+19) & 31], b, acc[19]); \
        acc[20] = fmaf(w[((u)+20) & 31], b, acc[20]); \
        acc[21] = fmaf(w[((u)+21) & 31], b, acc[21]); \
        acc[22] = fmaf(w[((u)+22) & 31], b, acc[22]); \
        acc[23] = fmaf(w[((u)+23) & 31], b, acc[23]); \
        acc[24] = fmaf(w[((u)+24) & 31], b, acc[24]); \
        acc[25] = fmaf(w[((u)+25) & 31], b, acc[25]); \
        acc[26] = fmaf(w[((u)+26) & 31], b, acc[26]); \
        acc[27] = fmaf(w[((u)+27) & 31], b, acc[27]); \
        acc[28] = fmaf(w[((u)+28) & 31], b, acc[28]); \
        acc[29] = fmaf(w[((u)+29) & 31], b, acc[29]); \
        acc[30] = fmaf(w[((u)+30) & 31], b, acc[30]); \
        acc[31] = fmaf(w[((u)+31) & 31], b, acc[31]); \
        w[(u)] = nw; }

    for (int t = 0; t < NT0; t += TDT) {
        STEP( 0) STEP( 1) STEP( 2) STEP( 3) STEP( 4) STEP( 5) STEP( 6) STEP( 7)
        STEP( 8) STEP( 9) STEP(10) STEP(11) STEP(12) STEP(13) STEP(14) STEP(15)
        STEP(16) STEP(17) STEP(18) STEP(19) STEP(20) STEP(21) STEP(22) STEP(23)
        STEP(24) STEP(25) STEP(26) STEP(27) STEP(28) STEP(29) STEP(30) STEP(31)
    }
#undef STEP

    // block-reduce each lag, then one atomic per lag
    __shared__ float part[4][TDT];
    const int lane = threadIdx.x & 63, wid = threadIdx.x >> 6;
    #pragma unroll
    for (int j = 0; j < TDT; ++j) {
        float v = acc[j];
        #pragma unroll
        for (int off = 32; off >= 1; off >>= 1) v += __shfl_xor(v, off, 64);
        if (lane == 0) part[wid][j] = v;
    }
    __syncthreads();
    if (threadIdx.x < TDT) {
        const float s = part[0][threadIdx.x] + part[1][threadIdx.x] +
                        part[2][threadIdx.x] + part[3][threadIdx.x];
        atomicAdd(&C[td0 + threadIdx.x], s);
    }
}

// msd[td] = (P[td] + Q - 2*C[td]) / (NT0*CH)  — one block per td, tree reduce
__global__ __launch_bounds__(256) void combine_kernel(const float* __restrict__ S,
                                                      const float* __restrict__ C,
                                                      float* __restrict__ out) {
    const int td = blockIdx.x;
    float p = 0.f, q = 0.f;
    for (int t = threadIdx.x; t < NT0; t += 256) {
        p += S[t + td];
        q += S[t];
    }
    #pragma unroll
    for (int off = 32; off >= 1; off >>= 1) {
        p += __shfl_xor(p, off, 64);
        q += __shfl_xor(q, off, 64);
    }
    __shared__ float pp[4], qq[4];
    const int lane = threadIdx.x & 63, wid = threadIdx.x >> 6;
    if (lane == 0) { pp[wid] = p; qq[wid] = q; }
    __syncthreads();
    if (threadIdx.x == 0) {
        const float P = pp[0] + pp[1] + pp[2] + pp[3];
        const float Q = qq[0] + qq[1] + qq[2] + qq[3];
        const float inv_M = 1.0f / ((float)NT0 * (float)CH);
        out[td] = (P + Q - 2.0f * C[td]) * inv_M;
    }
}

extern "C" void kernel_launch(void* const* d_in, const int* in_sizes, int n_in,
                              void* d_out, int out_size, void* d_ws, size_t ws_size,
                              hipStream_t stream) {
    const float* x = (const float*)d_in[0];
    float* out = (float*)d_out;
    float* S = (float*)d_ws;            // 4096 floats
    float* C = S + T_TOTAL;             // 1024 floats

    init_kernel<<<dim3((TD_MAXL + 255) / 256), dim3(256), 0, stream>>>(C);
    s_kernel<<<dim3(T_TOTAL), dim3(256), 0, stream>>>(x, S);
    cross_kernel<<<dim3(TD_MAXL / TDT * CH / 256), dim3(256), 0, stream>>>(x, C);
    combine_kernel<<<dim3(TD_MAXL), dim3(256), 0, stream>>>(S, C, out);
}

// Round 5
// 281.575 us; speedup vs baseline: 4.5493x; 2.8065x over previous
//
#include <hip/hip_runtime.h>

#define T_TOTAL 4096
#define NT0     3072
#define CH      6144
#define TD_MAXL 1024

// ---- MFMA band-Gram parameters ----
#define KS     4            // K-split
#define KC     (CH / KS)    // 1536 per block
#define BK     32           // K per step (one 16x16x32 MFMA)
#define NSTEP  (KC / BK)    // 48
#define NTI    24           // I tiles (i < 3072)
#define ND     9            // diagonal tiles (td < 1024 + in-tile offset)
#define NTILE  (NTI * ND)   // 216
#define NBLK   (NTILE * KS) // 864
#define LDH    40           // LDS row stride in fp16 (32 data + 8 pad -> 80 B, 2-way max)

typedef _Float16 half8 __attribute__((ext_vector_type(8)));
typedef float    f32x4 __attribute__((ext_vector_type(4)));

// d_ws layout: S[0..4095] (fp32), C[4096..5119] (fp32)

__global__ __launch_bounds__(256) void init_kernel(float* __restrict__ Cbuf) {
    int i = blockIdx.x * 256 + threadIdx.x;
    if (i < TD_MAXL) Cbuf[i] = 0.0f;
}

// S[t] = sum_ch x[t,ch]^2   (4096 blocks, one per t), float4 loads
__global__ __launch_bounds__(256) void s_kernel(const float* __restrict__ x,
                                                float* __restrict__ S) {
    const int t = blockIdx.x;
    const float4* row = (const float4*)(x + (size_t)t * CH);   // 1536 float4
    float s = 0.f;
    for (int k = threadIdx.x; k < CH / 4; k += 256) {
        float4 v = row[k];
        s = fmaf(v.x, v.x, s);
        s = fmaf(v.y, v.y, s);
        s = fmaf(v.z, v.z, s);
        s = fmaf(v.w, v.w, s);
    }
    #pragma unroll
    for (int off = 32; off >= 1; off >>= 1) s += __shfl_xor(s, off, 64);
    __shared__ float part[4];
    const int lane = threadIdx.x & 63, wid = threadIdx.x >> 6;
    if (lane == 0) part[wid] = s;
    __syncthreads();
    if (threadIdx.x == 0) S[t] = part[0] + part[1] + part[2] + part[3];
}

__device__ inline half8 pack8(const float4 u, const float4 v) {
    half8 h;
    h[0] = (_Float16)u.x; h[1] = (_Float16)u.y; h[2] = (_Float16)u.z; h[3] = (_Float16)u.w;
    h[4] = (_Float16)v.x; h[5] = (_Float16)v.y; h[6] = (_Float16)v.z; h[7] = (_Float16)v.w;
    return h;   // scalar casts = v_cvt_f16_f32 (RNE; RTZ packed cvt would bias msd[0] ~1e-3)
}

// Band Gram via MFMA: tile (I, D) computes G[i, j] for i in [128I,128I+128),
// j in [128(I+D), +128); diagonal sums j-i=td accumulated into C[td].
// 4 waves, each owns a 64x64 quadrant = 4x4 fragments of 16x16x32_f16.
__global__ __launch_bounds__(256, 2) void cross_mfma(const float* __restrict__ x,
                                                     float* __restrict__ C) {
    __shared__ _Float16 As[2][128][LDH];
    __shared__ _Float16 Bs[2][128][LDH];
    __shared__ float    C_loc[256];

    const int tid = threadIdx.x;

    // XCD-chunked decode: HW round-robins bid%8 across XCDs; give each XCD
    // 27 consecutive tiles (3 I-panels) x 4 K-chunks for L2 reuse.
    const int bid  = blockIdx.x;          // 0..863
    const int xcd  = bid & 7;
    const int slot = bid >> 3;            // 0..107
    const int ks   = slot / 27;           // 0..3
    const int tt   = slot % 27;
    const int tile = xcd * 27 + tt;       // 0..215 (bijective)
    const int I    = tile / ND;           // 0..23
    const int D    = tile % ND;           // 0..8
    const int i0 = I * 128, j0 = (I + D) * 128;
    const int k0 = ks * KC;

    C_loc[tid] = 0.f;                     // visible by first __syncthreads()

    // staging: 2 threads/row, 16 consecutive floats each (4x float4, coalesced)
    const int srow = tid >> 1;            // 0..127
    const int skq  = (tid & 1) << 4;      // 0 or 16
    const float* gA = x + (size_t)(i0 + srow) * CH + k0 + skq;
    const float* gB = x + (size_t)(j0 + srow) * CH + k0 + skq;

    // wave/fragment decomposition
    const int lane = tid & 63, wid = tid >> 6;
    const int wm = wid >> 1, wn = wid & 1;       // 2x2 waves of 64x64
    const int fr = lane & 15, ss = lane >> 4;    // frag row/col + k-slot
    const int rowA = wm * 64 + fr;
    const int rowB = wn * 64 + fr;

    f32x4 acc[4][4];
    #pragma unroll
    for (int m = 0; m < 4; ++m)
        #pragma unroll
        for (int n = 0; n < 4; ++n) acc[m][n] = (f32x4)0.f;

    // prologue: stage step 0 into buffer 0
    {
        float4 a[4], b[4];
        #pragma unroll
        for (int q = 0; q < 4; ++q) {
            a[q] = ((const float4*)gA)[q];
            b[q] = ((const float4*)gB)[q];
        }
        *(half8*)&As[0][srow][skq]     = pack8(a[0], a[1]);
        *(half8*)&As[0][srow][skq + 8] = pack8(a[2], a[3]);
        *(half8*)&Bs[0][srow][skq]     = pack8(b[0], b[1]);
        *(half8*)&Bs[0][srow][skq + 8] = pack8(b[2], b[3]);
    }

    int cur = 0;
    for (int t = 0; t < NSTEP; ++t) {
        // issue next-step global loads early (hide HBM/L2 latency under MFMA)
        float4 a[4], b[4];
        const bool more = (t + 1 < NSTEP);
        if (more) {
            const float* pA = gA + (size_t)(t + 1) * BK;
            const float* pB = gB + (size_t)(t + 1) * BK;
            #pragma unroll
            for (int q = 0; q < 4; ++q) {
                a[q] = ((const float4*)pA)[q];
                b[q] = ((const float4*)pB)[q];
            }
        }
        __syncthreads();    // buf[cur] writes (prev iter) visible; prev reads done

        half8 fA[4], fB[4];
        #pragma unroll
        for (int m = 0; m < 4; ++m)
            fA[m] = *(const half8*)&As[cur][rowA + 16 * m][ss * 8];
        #pragma unroll
        for (int n = 0; n < 4; ++n)
            fB[n] = *(const half8*)&Bs[cur][rowB + 16 * n][ss * 8];
        #pragma unroll
        for (int m = 0; m < 4; ++m)
            #pragma unroll
            for (int n = 0; n < 4; ++n)
                acc[m][n] = __builtin_amdgcn_mfma_f32_16x16x32_f16(fA[m], fB[n],
                                                                   acc[m][n], 0, 0, 0);
        if (more) {
            const int nb = cur ^ 1;
            *(half8*)&As[nb][srow][skq]     = pack8(a[0], a[1]);
            *(half8*)&As[nb][srow][skq + 8] = pack8(a[2], a[3]);
            *(half8*)&Bs[nb][srow][skq]     = pack8(b[0], b[1]);
            *(half8*)&Bs[nb][srow][skq + 8] = pack8(b[2], b[3]);
        }
        cur ^= 1;
    }

    // epilogue: diagonal sums. i_loc = 64wm+16m+4ss+r, j_loc = 64wn+16n+fr
    // o = j_loc - i_loc = 64(wn-wm) + 16(n-m) + (fr - 4ss) - r  in (-128,128)
    float buck[7][4];
    #pragma unroll
    for (int dd = 0; dd < 7; ++dd)
        #pragma unroll
        for (int rr = 0; rr < 4; ++rr) buck[dd][rr] = 0.f;
    #pragma unroll
    for (int m = 0; m < 4; ++m)
        #pragma unroll
        for (int n = 0; n < 4; ++n)
            #pragma unroll
            for (int rr = 0; rr < 4; ++rr)
                buck[n - m + 3][rr] += acc[m][n][rr];

    const int obase = 64 * (wn - wm) + 128 + (fr - (ss << 2));
    #pragma unroll
    for (int dd = 0; dd < 7; ++dd)
        #pragma unroll
        for (int rr = 0; rr < 4; ++rr)
            atomicAdd(&C_loc[obase + 16 * (dd - 3) - rr], buck[dd][rr]);
    __syncthreads();

    const int td = D * 128 + tid - 128;   // masks D=0 lower triangle & td>=1024
    if (td >= 0 && td < TD_MAXL) atomicAdd(&C[td], C_loc[tid]);
}

// msd[td] = (P[td] + Q - 2*C[td]) / (NT0*CH)  — one block per td, tree reduce
__global__ __launch_bounds__(256) void combine_kernel(const float* __restrict__ S,
                                                      const float* __restrict__ C,
                                                      float* __restrict__ out) {
    const int td = blockIdx.x;
    float p = 0.f, q = 0.f;
    for (int t = threadIdx.x; t < NT0; t += 256) {
        p += S[t + td];
        q += S[t];
    }
    #pragma unroll
    for (int off = 32; off >= 1; off >>= 1) {
        p += __shfl_xor(p, off, 64);
        q += __shfl_xor(q, off, 64);
    }
    __shared__ float pp[4], qq[4];
    const int lane = threadIdx.x & 63, wid = threadIdx.x >> 6;
    if (lane == 0) { pp[wid] = p; qq[wid] = q; }
    __syncthreads();
    if (threadIdx.x == 0) {
        const float P = pp[0] + pp[1] + pp[2] + pp[3];
        const float Q = qq[0] + qq[1] + qq[2] + qq[3];
        const float inv_M = 1.0f / ((float)NT0 * (float)CH);
        out[td] = (P + Q - 2.0f * C[td]) * inv_M;
    }
}

extern "C" void kernel_launch(void* const* d_in, const int* in_sizes, int n_in,
                              void* d_out, int out_size, void* d_ws, size_t ws_size,
                              hipStream_t stream) {
    const float* x = (const float*)d_in[0];
    float* out = (float*)d_out;
    float* S = (float*)d_ws;            // 4096 floats
    float* C = S + T_TOTAL;             // 1024 floats

    init_kernel<<<dim3((TD_MAXL + 255) / 256), dim3(256), 0, stream>>>(C);
    s_kernel<<<dim3(T_TOTAL), dim3(256), 0, stream>>>(x, S);
    cross_mfma<<<dim3(NBLK), dim3(256), 0, stream>>>(x, C);
    combine_kernel<<<dim3(TD_MAXL), dim3(256), 0, stream>>>(S, C, out);
}